// Round 2
// baseline (369.485 us; speedup 1.0000x reference)
//
#include <hip/hip_runtime.h>

// Max-unpooling (SegNet) scatter. B=32, H=W=64, C=128.
//   image_size = H*W*C        = 2^19  (per-batch pooled elements)
//   out_image  = 4*image_size = 2^21  (per-batch output elements)
// Output flat index = b*out_image + (am mod out_image).
//
// R3 changes (theory: workgroup-dispatch-rate bound, not BW bound):
//  - Previous version launched 65,536 one-float4-per-thread blocks for BOTH
//    kernels; each kernel took ~160 us (zero_out: 268 MB @ ~1.6 TB/s) while
//    __amd_rocclr_fillBufferAligned streamed 1 GiB in the same 165 us
//    (6.5 TB/s) using a grid-stride loop. Diagnosis: ~WG-launch-rate floor
//    at 65,536 WGs per kernel.
//  - Fix: grid-stride loops at 2048 blocks x 256 threads (8 blocks/CU).
//    zero_out: 32 float4/thread; scatter: 8 groups/thread.
//  - Nontemporal stores for streaming output writes (no reuse), nontemporal
//    loads for values/argmax (read-once).
// R4 fix: __builtin_nontemporal_* requires native clang vector types, not
//    HIP_vector_type structs -> use ext_vector_type f32x4/i32x4.
// Predicted: zero_out ~45 us @ ~78% HBM peak, scatter ~38 us, dur_us ~95.

#define IMAGE_SHIFT 19
#define OUTIMG_SHIFT 21
#define OUTIMG_MASK ((1 << OUTIMG_SHIFT) - 1)

typedef float f32x4 __attribute__((ext_vector_type(4)));
typedef int   i32x4 __attribute__((ext_vector_type(4)));

__global__ __launch_bounds__(256) void zero_out(f32x4* __restrict__ out, int n4)
{
    const int stride = gridDim.x * blockDim.x;
    const f32x4 z = {0.f, 0.f, 0.f, 0.f};
    for (int t = blockIdx.x * blockDim.x + threadIdx.x; t < n4; t += stride) {
        __builtin_nontemporal_store(z, &out[t]);
    }
}

__global__ __launch_bounds__(256) void unpool_scatter(
    const f32x4* __restrict__ values,
    const i32x4* __restrict__ argmax,
    float*       __restrict__ out,
    int n4)
{
    const int stride = gridDim.x * blockDim.x;
    for (int t = blockIdx.x * blockDim.x + threadIdx.x; t < n4; t += stride) {
        f32x4 v = __builtin_nontemporal_load(&values[t]);
        i32x4 a = __builtin_nontemporal_load(&argmax[t]);

        int base_elem = t << 2;
        int b     = base_elem >> IMAGE_SHIFT;
        int obase = b << OUTIMG_SHIFT;

        int ix = a.x & OUTIMG_MASK;
        int iy = a.y & OUTIMG_MASK;
        int iz = a.z & OUTIMG_MASK;
        int iw = a.w & OUTIMG_MASK;

        // Fast path: 4 contiguous, 16B-aligned targets -> one float4 store.
        // (Holds when the 4 elements are consecutive channels of one output
        // position; degrades gracefully otherwise.)
        if (((ix & 3) == 0) && iy == ix + 1 && iz == ix + 2 && iw == ix + 3) {
            __builtin_nontemporal_store(v, (f32x4*)(out + obase + ix));
        } else {
            out[obase + ix] = v.x;
            out[obase + iy] = v.y;
            out[obase + iz] = v.z;
            out[obase + iw] = v.w;
        }
    }
}

extern "C" void kernel_launch(void* const* d_in, const int* in_sizes, int n_in,
                              void* d_out, int out_size, void* d_ws, size_t ws_size,
                              hipStream_t stream) {
    const float* values = (const float*)d_in[0];
    const int*   argmax = (const int*)d_in[1];
    float*       out    = (float*)d_out;

    int n  = in_sizes[0];         // 16,777,216 pooled elements
    int n4 = n >> 2;              // 4,194,304 float4 groups

    int on4 = out_size >> 2;      // 16,777,216 output float4s

    const int block  = 256;
    const int blocks = 2048;      // 8 blocks/CU on 256 CUs; grid-stride the rest

    zero_out<<<blocks, block, 0, stream>>>((f32x4*)out, on4);

    unpool_scatter<<<blocks, block, 0, stream>>>(
        (const f32x4*)values, (const i32x4*)argmax, out, n4);
}